// Round 7
// baseline (218.931 us; speedup 1.0000x reference)
//
#include <hip/hip_runtime.h>
#include <hip/hip_bf16.h>

typedef __bf16 bf16x8 __attribute__((ext_vector_type(8)));
typedef __bf16 bf16x4 __attribute__((ext_vector_type(4)));
typedef float  f32x4  __attribute__((ext_vector_type(4)));

#define DM 1024
#define PD 3328
#define TROWS 8192   // bs*seq = 2*4096
#define SEQ 4096

template <int N> struct ic_t { static constexpr int v = N; };

__device__ __forceinline__ float sigmoidf(float x) { return 1.f / (1.f + __expf(-x)); }

__device__ __forceinline__ void gload16(const void* g, void* l) {
  __builtin_amdgcn_global_load_lds(
      (const __attribute__((address_space(1))) void*)g,
      (__attribute__((address_space(3))) void*)l, 16, 0, 0);
}

template <int N>
__device__ __forceinline__ void vmwait() {
  if constexpr (N == 0)      asm volatile("s_waitcnt vmcnt(0)" ::: "memory");
  else if constexpr (N == 3) asm volatile("s_waitcnt vmcnt(3)" ::: "memory");
  else if constexpr (N == 4) asm volatile("s_waitcnt vmcnt(4)" ::: "memory");
  else if constexpr (N == 6) asm volatile("s_waitcnt vmcnt(6)" ::: "memory");
  else if constexpr (N == 8) asm volatile("s_waitcnt vmcnt(8)" ::: "memory");
  else static_assert(N == 0 || N == 3 || N == 4 || N == 6 || N == 8, "add case");
}

__device__ __forceinline__ void wgbar() {
  asm volatile("" ::: "memory");
  __builtin_amdgcn_s_barrier();
  asm volatile("" ::: "memory");
}

// ---------------- transpose + f32->bf16 convert:  in[K][N] f32 -> out[N][K] bf16
__global__ __launch_bounds__(256) void tcvt_kernel(const float* __restrict__ in,
                                                   __bf16* __restrict__ out,
                                                   int K, int N) {
  __shared__ float tile[32][33];
  int n0 = blockIdx.x * 32, k0 = blockIdx.y * 32;
  int tx = threadIdx.x, ty = threadIdx.y;     // 32 x 8
  for (int i = ty; i < 32; i += 8) tile[i][tx] = in[(size_t)(k0 + i) * N + n0 + tx];
  __syncthreads();
  for (int i = ty; i < 32; i += 8) out[(size_t)(n0 + i) * K + k0 + tx] = (__bf16)tile[tx][i];
}

// ---------------- RMSNorm -> bf16
__global__ __launch_bounds__(256) void rmsnorm_kernel(const float* __restrict__ hidden,
                                                      const float* __restrict__ w,
                                                      __bf16* __restrict__ hbf) {
  int r = blockIdx.x;
  int tid = threadIdx.x;
  float4 v = ((const float4*)(hidden + (size_t)r * DM))[tid];
  float ss = v.x * v.x + v.y * v.y + v.z * v.z + v.w * v.w;
#pragma unroll
  for (int off = 32; off > 0; off >>= 1) ss += __shfl_xor(ss, off);
  __shared__ float wsum[4];
  int lane = tid & 63, wid = tid >> 6;
  if (lane == 0) wsum[wid] = ss;
  __syncthreads();
  float tot = wsum[0] + wsum[1] + wsum[2] + wsum[3];
  float inv = rsqrtf(tot * (1.f / 1024.f) + 1e-6f);
  float4 wl = ((const float4*)w)[tid];
  bf16x4 o;
  o[0] = (__bf16)(v.x * inv * wl.x);
  o[1] = (__bf16)(v.y * inv * wl.y);
  o[2] = (__bf16)(v.z * inv * wl.z);
  o[3] = (__bf16)(v.w * inv * wl.w);
  *(bf16x4*)(hbf + (size_t)r * DM + tid * 4) = o;
}

// ---------------- 4-phase counted-vmcnt MFMA GEMM (T2+T3+T4+T5).
// Tile BM x BN, BK=64 split in two K-halves, each LDS-resident as a
// physically-contiguous block [rows][32] packed as [row-pairs][8 x 16B slots]
// with pair-XOR swizzle phi = ((r&1)*4+h) ^ ((r>>1)&7): DMA-linear per half,
// ds_read_b128 spreads 8 lanes per 16B slot (conflict-free schedule).
// 8 waves (2m x 4n), per-wave output 128 x (BN/4).
// Per K-tile: P0{ldA kh0, ldB g0, stage A(t+1)kh1, 16*NG MFMA}
//             P1{ldB g1, stage B(t+1)kh1, vmcnt(FULL)}
//             P2{ldA kh1, ldB g0, stage A(t+2)kh0}
//             P3{ldB g1, stage B(t+2)kh0, vmcnt(FULL)}
// vmcnt derivation (FIFO, loads/thread per stage: A=SA, B=SB):
//   P1 guards kh1(t)  (issued t-1:P0/P1): newer = t-1:P2,P3 + t:P0,P1 = 2(SA+SB)
//   P3 guards kh0(t+1)(issued t-1:P2/P3): newer = t:P0..P3        = 2(SA+SB)
// Tails: t=NT-2: P3 -> SA+SB.  t=NT-1: P1 -> 0, P3 -> none.
template <int BM, int BN, int EPI>
__global__ __launch_bounds__(512, 2) void gemm4p(
    const __bf16* __restrict__ A, const __bf16* __restrict__ Bt,
    int N_out, int K,
    const float* __restrict__ gate_bias, const float* __restrict__ shortcut,
    float* __restrict__ outf, __bf16* __restrict__ zbf, __bf16* __restrict__ xbf,
    __bf16* __restrict__ gbf, __bf16* __restrict__ qbf, __bf16* __restrict__ kbf) {
  constexpr int NF = BN / 64;          // n-frags per wave (4 or 2)
  constexpr int NG = NF / 2;           // n-frags per phase
  constexpr int SA = BM / 128;         // loads/thread per A half-stage
  constexpr int SB = BN / 128;
  constexpr int FULL = 2 * (SA + SB);
  constexpr int HALF = SA + SB;

  __shared__ __bf16 As[2][2][BM * 32];
  __shared__ __bf16 Bs[2][2][BN * 32];

  const int tid = threadIdx.x;
  const int lane = tid & 63, wid = tid >> 6;
  const int wm = wid >> 2, wn = wid & 3;
  const int lr = lane & 15, hh = lane >> 4;

  // XCD-aware swizzle (grid multiples of 8)
  const int nwg = gridDim.x, cpx = nwg >> 3;
  const int swz = (blockIdx.x & 7) * cpx + (blockIdx.x >> 3);
  const int ntx = N_out / BN;
  const int m0 = (swz / ntx) * BM, n0 = (swz % ntx) * BN;

  const int NT = K >> 6;
  f32x4 acc[8][NF] = {};
  bf16x8 afr[8];

  const int arow = wm * 128 + lr;
  const int brow = wn * (BN / 4) + lr;

  // stage one K-half (32 cols) of ROWS rows into a contiguous LDS half-block
  auto stage_half = [&](const __bf16* src, int rows_unused, int row0, int kcol,
                        __bf16* hp, int nloads) {
    (void)rows_unused;
#pragma unroll
    for (int j = 0; j < 2; ++j) {
      if (j < nloads) {
        int c = tid + j * 512;
        int p = c >> 3, phi = c & 7;
        int lam = phi ^ (p & 7);
        int r = 2 * p + (lam >> 2), s = lam & 3;
        gload16(&src[(size_t)(row0 + r) * K + kcol + s * 8], hp + c * 8);
      }
    }
  };
  auto fragrd = [&](const __bf16* hp, int r) -> bf16x8 {
    int p = r >> 1;
    int phi = (((r & 1) << 2) | hh) ^ (p & 7);
    return *(const bf16x8*)&hp[(p << 6) + (phi << 3)];
  };

  // prologue: kh0(0), kh1(0), kh0(1) for A and B, in the loop's FIFO order
  stage_half(A,  0, m0, 0,  &As[0][0][0], SA);
  stage_half(Bt, 0, n0, 0,  &Bs[0][0][0], SB);
  stage_half(A,  0, m0, 32, &As[0][1][0], SA);
  stage_half(Bt, 0, n0, 32, &Bs[0][1][0], SB);
  stage_half(A,  0, m0, 64, &As[1][0][0], SA);
  stage_half(Bt, 0, n0, 64, &Bs[1][0][0], SB);
  vmwait<FULL>();   // oldest SA+SB loads (kh0 of tile 0) landed
  wgbar();

  auto phase = [&](int t, auto kkc, auto ngc, auto stg, auto vmw) {
    constexpr int kk = decltype(kkc)::v;
    constexpr int ngi = decltype(ngc)::v;
    const __bf16* Ah = &As[t & 1][kk][0];
    const __bf16* Bh = &Bs[t & 1][kk][0];
    if constexpr (ngi == 0) {
#pragma unroll
      for (int mf = 0; mf < 8; ++mf) afr[mf] = fragrd(Ah, arow + mf * 16);
    }
    bf16x8 bfr[NG];
#pragma unroll
    for (int g = 0; g < NG; ++g) bfr[g] = fragrd(Bh, brow + (ngi * NG + g) * 16);
    stg();
    vmw();
    wgbar();
    __builtin_amdgcn_s_setprio(1);
#pragma unroll
    for (int mf = 0; mf < 8; ++mf)
#pragma unroll
      for (int g = 0; g < NG; ++g)
        acc[mf][ngi * NG + g] = __builtin_amdgcn_mfma_f32_16x16x32_bf16(
            afr[mf], bfr[g], acc[mf][ngi * NG + g], 0, 0, 0);
    __builtin_amdgcn_s_setprio(0);
    wgbar();
  };
  auto nostg = [] {};
  auto nowait = [] {};

  for (int t = 0; t + 2 < NT; ++t) {
    int k1 = ((t + 1) << 6) + 32, k2 = (t + 2) << 6;
    phase(t, ic_t<0>{}, ic_t<0>{},
          [&] { stage_half(A, 0, m0, k1, &As[(t + 1) & 1][1][0], SA); }, nowait);
    phase(t, ic_t<0>{}, ic_t<1>{},
          [&] { stage_half(Bt, 0, n0, k1, &Bs[(t + 1) & 1][1][0], SB); },
          [] { vmwait<FULL>(); });
    phase(t, ic_t<1>{}, ic_t<0>{},
          [&] { stage_half(A, 0, m0, k2, &As[t & 1][0][0], SA); }, nowait);
    phase(t, ic_t<1>{}, ic_t<1>{},
          [&] { stage_half(Bt, 0, n0, k2, &Bs[t & 1][0][0], SB); },
          [] { vmwait<FULL>(); });
  }
  {  // t = NT-2: stage only kh1(NT-1)
    int t = NT - 2;
    int k1 = ((t + 1) << 6) + 32;
    phase(t, ic_t<0>{}, ic_t<0>{},
          [&] { stage_half(A, 0, m0, k1, &As[(t + 1) & 1][1][0], SA); }, nowait);
    phase(t, ic_t<0>{}, ic_t<1>{},
          [&] { stage_half(Bt, 0, n0, k1, &Bs[(t + 1) & 1][1][0], SB); },
          [] { vmwait<FULL>(); });
    phase(t, ic_t<1>{}, ic_t<0>{}, nostg, nowait);
    phase(t, ic_t<1>{}, ic_t<1>{}, nostg, [] { vmwait<HALF>(); });
  }
  {  // t = NT-1: no staging
    int t = NT - 1;
    phase(t, ic_t<0>{}, ic_t<0>{}, nostg, nowait);
    phase(t, ic_t<0>{}, ic_t<1>{}, nostg, [] { vmwait<0>(); });
    phase(t, ic_t<1>{}, ic_t<0>{}, nostg, nowait);
    phase(t, ic_t<1>{}, ic_t<1>{}, nostg, nowait);
  }

  // epilogue: C/D map col=lane&15, row=(lane>>4)*4+i
#pragma unroll
  for (int mf = 0; mf < 8; ++mf) {
#pragma unroll
    for (int nf = 0; nf < NF; ++nf) {
#pragma unroll
      for (int i = 0; i < 4; ++i) {
        int r = m0 + wm * 128 + mf * 16 + (hh << 2) + i;
        int c = n0 + wn * (BN / 4) + nf * 16 + lr;
        float v = acc[mf][nf][i];
        if (EPI == 1) {
          if (c < 1024)       zbf[(size_t)r * DM + c] = (__bf16)sigmoidf(v);
          else if (c < 2048)  xbf[(size_t)r * DM + (c - 1024)] = (__bf16)v;
          else if (c < 3072)  gbf[(size_t)r * DM + (c - 2048)] = (__bf16)sigmoidf(v + gate_bias[c - 2048]);
          else if (c < 3200)  qbf[(size_t)r * 128 + (c - 3072)] = (__bf16)v;
          else                kbf[(size_t)r * 128 + (c - 3200)] = (__bf16)v;
        } else {
          outf[(size_t)r * DM + c] = v + shortcut[(size_t)r * DM + c];
        }
      }
    }
  }
}

// ---------------- per-chunk first-order scan (f32 state), thread = one d-channel
__global__ __launch_bounds__(256) void scan_kernel(const __bf16* __restrict__ g,
                                                   const __bf16* __restrict__ x,
                                                   const __bf16* __restrict__ kin,
                                                   __bf16* __restrict__ ixa,
                                                   __bf16* __restrict__ ika) {
  int bx = blockIdx.x;            // 2*64*4 = 512 blocks
  int part = bx & 3;
  int c = (bx >> 2) & 63;
  int b = bx >> 8;
  int d = part * 256 + threadIdx.x;
  size_t base = (size_t)b * SEQ + (size_t)c * 64;
  float sx = 0.f, sk = 0.f;
  for (int t = 0; t < 64; ++t) {
    size_t row = base + t;
    float gg = (float)g[row * DM + d];
    float xv = (float)x[row * DM + d];
    float kv = (float)kin[row * 128 + (d & 127)];
    sx = gg * (sx - xv) + xv;   // = g*prev + (1-g)*x
    sk = gg * (sk - kv) + kv;
    ixa[row * DM + d] = (__bf16)sx;
    ika[row * DM + d] = (__bf16)sk;
  }
}

// ---------------- attention: block = (qtile 64 queries, head, batch); 4 waves
__global__ __launch_bounds__(256) void attn_kernel(const __bf16* __restrict__ qbf,
                                                   const __bf16* __restrict__ ixa,
                                                   const __bf16* __restrict__ ika,
                                                   const __bf16* __restrict__ zbf,
                                                   __bf16* __restrict__ y) {
  const int qt = blockIdx.x;   // 0..63 query chunk
  const int h  = blockIdx.y;   // 0..15
  const int b  = blockIdx.z;   // 0..1
  const int tid = threadIdx.x;
  const int lane = tid & 63, wd = tid >> 6;

  __shared__ __bf16 qs[64 * 72];
  __shared__ __bf16 ck[64 * 72];
  __shared__ __bf16 cxT[64 * 72];
  __shared__ __bf16 pb[64 * 72];
  __shared__ float sc[64 * 65];
  __shared__ float rden[64], iwd[64];

  const size_t base = (size_t)b * SEQ;

  for (int i = tid; i < 512; i += 256) {
    int row = i >> 3, part = i & 7;
    *(bf16x8*)&qs[row * 72 + part * 8] =
        *(const bf16x8*)&qbf[(base + qt * 64 + row) * 128 + (h & 1) * 64 + part * 8];
    *(bf16x8*)&ck[row * 72 + part * 8] =
        *(const bf16x8*)&ika[(base + (size_t)row * 64) * DM + h * 64 + part * 8];
  }
  for (int i = tid; i < 4096; i += 256) {
    int c = i & 63, j = i >> 6;
    cxT[j * 72 + c] = ixa[(base + (size_t)c * 64) * DM + h * 64 + j];
  }
  __syncthreads();

  {
    f32x4 d4[4] = {};
#pragma unroll
    for (int kk = 0; kk < 64; kk += 32) {
      bf16x8 a = *(const bf16x8*)&qs[(wd * 16 + (lane & 15)) * 72 + kk + (lane >> 4) * 8];
#pragma unroll
      for (int ni = 0; ni < 4; ++ni) {
        bf16x8 bb = *(const bf16x8*)&ck[(ni * 16 + (lane & 15)) * 72 + kk + (lane >> 4) * 8];
        d4[ni] = __builtin_amdgcn_mfma_f32_16x16x32_bf16(a, bb, d4[ni], 0, 0, 0);
      }
    }
#pragma unroll
    for (int ni = 0; ni < 4; ++ni)
#pragma unroll
      for (int i = 0; i < 4; ++i) {
        int qrow = wd * 16 + (lane >> 4) * 4 + i;
        int c = ni * 16 + (lane & 15);
        sc[qrow * 65 + c] = 0.125f * d4[ni][i];
      }
  }

  float lse = 0.f;
  if (tid < 64) {
    const __bf16* qrow = &qbf[(base + qt * 64 + tid) * 128 + (h & 1) * 64];
    const __bf16* krow = &ika[(base + qt * 64 + tid) * DM + h * 64];
    float dot = 0.f;
#pragma unroll
    for (int p = 0; p < 8; ++p) {
      bf16x8 qa = *(const bf16x8*)&qrow[p * 8];
      bf16x8 ka = *(const bf16x8*)&krow[p * 8];
#pragma unroll
      for (int e = 0; e < 8; ++e) dot += (float)qa[e] * (float)ka[e];
    }
    lse = 0.125f * dot;
  }
  __syncthreads();

  if (tid < 64) {
    int q = tid;
    float m = lse;
    for (int c = 0; c < qt; ++c) m = fmaxf(m, sc[q * 65 + c]);
    float den = 0.f;
    for (int c = 0; c < 64; ++c) {
      float wv = (c < qt) ? __expf(sc[q * 65 + c] - m) : 0.f;
      pb[q * 72 + c] = (__bf16)wv;
      den += wv;
    }
    float iw = __expf(lse - m);
    den += iw;
    rden[q] = 1.f / den;
    iwd[q] = iw;
  }
  __syncthreads();

  {
    f32x4 d4[4] = {};
#pragma unroll
    for (int kk = 0; kk < 64; kk += 32) {
      bf16x8 a = *(const bf16x8*)&pb[(wd * 16 + (lane & 15)) * 72 + kk + (lane >> 4) * 8];
#pragma unroll
      for (int ni = 0; ni < 4; ++ni) {
        bf16x8 bb = *(const bf16x8*)&cxT[(ni * 16 + (lane & 15)) * 72 + kk + (lane >> 4) * 8];
        d4[ni] = __builtin_amdgcn_mfma_f32_16x16x32_bf16(a, bb, d4[ni], 0, 0, 0);
      }
    }
#pragma unroll
    for (int ni = 0; ni < 4; ++ni)
#pragma unroll
      for (int i = 0; i < 4; ++i) {
        int qrow = wd * 16 + (lane >> 4) * 4 + i;
        int j = ni * 16 + (lane & 15);
        size_t srow = base + qt * 64 + qrow;
        float ix = (float)ixa[srow * DM + h * 64 + j];
        float outv = (d4[ni][i] + iwd[qrow] * ix) * rden[qrow];
        float zv = (float)zbf[srow * DM + h * 64 + j];
        y[srow * DM + h * 64 + j] = (__bf16)(outv * zv);
      }
  }
}

// ---------------- launcher
extern "C" void kernel_launch(void* const* d_in, const int* in_sizes, int n_in,
                              void* d_out, int out_size, void* d_ws, size_t ws_size,
                              hipStream_t stream) {
  const float* hidden = (const float*)d_in[0];
  const float* rmsw   = (const float*)d_in[1];
  const float* Win    = (const float*)d_in[2];
  const float* gbias  = (const float*)d_in[3];
  const float* Wout   = (const float*)d_in[4];
  float* out = (float*)d_out;

  char* ws = (char*)d_ws;
  size_t o = 0;
  auto alloc = [&](size_t bytes) { char* p = ws + o; o += (bytes + 255) & ~(size_t)255; return p; };
  __bf16* WinT  = (__bf16*)alloc((size_t)PD * DM * 2);
  __bf16* WoutT = (__bf16*)alloc((size_t)DM * DM * 2);
  __bf16* hy    = (__bf16*)alloc((size_t)TROWS * DM * 2);  // h_bf, reused as y after GEMM1
  __bf16* zbf   = (__bf16*)alloc((size_t)TROWS * DM * 2);
  __bf16* xbf   = (__bf16*)alloc((size_t)TROWS * DM * 2);
  __bf16* gbf   = (__bf16*)alloc((size_t)TROWS * DM * 2);
  __bf16* qbf   = (__bf16*)alloc((size_t)TROWS * 128 * 2);
  __bf16* kbf   = (__bf16*)alloc((size_t)TROWS * 128 * 2);
  __bf16* ixa   = (__bf16*)alloc((size_t)TROWS * DM * 2);
  __bf16* ika   = (__bf16*)alloc((size_t)TROWS * DM * 2);

  tcvt_kernel<<<dim3(PD / 32, DM / 32), dim3(32, 8), 0, stream>>>(Win, WinT, DM, PD);
  tcvt_kernel<<<dim3(DM / 32, DM / 32), dim3(32, 8), 0, stream>>>(Wout, WoutT, DM, DM);
  rmsnorm_kernel<<<TROWS, 256, 0, stream>>>(hidden, rmsw, hy);
  // GEMM1: M=8192, N=3328 -> (8192/256)*(3328/256) = 32*13 = 416 blocks (%8==0)
  gemm4p<256, 256, 1><<<dim3((TROWS / 256) * (PD / 256)), 512, 0, stream>>>(
      hy, WinT, PD, DM, gbias, nullptr, nullptr, zbf, xbf, gbf, qbf, kbf);
  scan_kernel<<<512, 256, 0, stream>>>(gbf, xbf, kbf, ixa, ika);
  attn_kernel<<<dim3(64, 16, 2), 256, 0, stream>>>(qbf, ixa, ika, zbf, hy);
  // GEMM2: M=8192, N=1024 -> (8192/256)*(1024/128) = 32*8 = 256 blocks (1/CU)
  gemm4p<256, 128, 0><<<dim3((TROWS / 256) * (DM / 128)), 512, 0, stream>>>(
      hy, WoutT, DM, DM, nullptr, hidden, out, nullptr, nullptr, nullptr, nullptr, nullptr);
}

// Round 8
// 206.738 us; speedup vs baseline: 1.0590x; 1.0590x over previous
//
#include <hip/hip_runtime.h>
#include <hip/hip_bf16.h>

typedef __bf16 bf16x8 __attribute__((ext_vector_type(8)));
typedef __bf16 bf16x4 __attribute__((ext_vector_type(4)));
typedef float  f32x4  __attribute__((ext_vector_type(4)));

#define DM 1024
#define PD 3328
#define TROWS 8192   // bs*seq = 2*4096
#define SEQ 4096

__device__ __forceinline__ float sigmoidf(float x) { return 1.f / (1.f + __expf(-x)); }

__device__ __forceinline__ void gload16(const void* g, void* l) {
  __builtin_amdgcn_global_load_lds(
      (const __attribute__((address_space(1))) void*)g,
      (__attribute__((address_space(3))) void*)l, 16, 0, 0);
}

// ---------------- transpose + f32->bf16 convert:  in[K][N] f32 -> out[N][K] bf16
__global__ __launch_bounds__(256) void tcvt_kernel(const float* __restrict__ in,
                                                   __bf16* __restrict__ out,
                                                   int K, int N) {
  __shared__ float tile[32][33];
  int n0 = blockIdx.x * 32, k0 = blockIdx.y * 32;
  int tx = threadIdx.x, ty = threadIdx.y;     // 32 x 8
  for (int i = ty; i < 32; i += 8) tile[i][tx] = in[(size_t)(k0 + i) * N + n0 + tx];
  __syncthreads();
  for (int i = ty; i < 32; i += 8) out[(size_t)(n0 + i) * K + k0 + tx] = (__bf16)tile[tx][i];
}

// ---------------- RMSNorm -> bf16
__global__ __launch_bounds__(256) void rmsnorm_kernel(const float* __restrict__ hidden,
                                                      const float* __restrict__ w,
                                                      __bf16* __restrict__ hbf) {
  int r = blockIdx.x;
  int tid = threadIdx.x;
  float4 v = ((const float4*)(hidden + (size_t)r * DM))[tid];
  float ss = v.x * v.x + v.y * v.y + v.z * v.z + v.w * v.w;
#pragma unroll
  for (int off = 32; off > 0; off >>= 1) ss += __shfl_xor(ss, off);
  __shared__ float wsum[4];
  int lane = tid & 63, wid = tid >> 6;
  if (lane == 0) wsum[wid] = ss;
  __syncthreads();
  float tot = wsum[0] + wsum[1] + wsum[2] + wsum[3];
  float inv = rsqrtf(tot * (1.f / 1024.f) + 1e-6f);
  float4 wl = ((const float4*)w)[tid];
  bf16x4 o;
  o[0] = (__bf16)(v.x * inv * wl.x);
  o[1] = (__bf16)(v.y * inv * wl.y);
  o[2] = (__bf16)(v.z * inv * wl.z);
  o[3] = (__bf16)(v.w * inv * wl.w);
  *(bf16x4*)(hbf + (size_t)r * DM + tid * 4) = o;
}

// ---------------- 2-phase MFMA GEMM, 128x128 tile, BK=32, dbuf LDS (32 KiB),
// ONE barrier per K-step. Parameter change from the verified R6 template:
// BK 64->32 halves LDS so FOUR blocks/CU are co-resident (32 waves/CU, max);
// each block's vmcnt(0) drain is covered by the other blocks' MFMA.
// With 64B rows (32 bf16), the fragment ds_read_b128 pattern is naturally
// uniform across banks (8 accesses/bank) -> no swizzle, fully linear staging.
template <int EPI>
__global__ __launch_bounds__(512, 8) void gemm2p(
    const __bf16* __restrict__ A, const __bf16* __restrict__ Bt,
    int N_out, int K,
    const float* __restrict__ gate_bias, const float* __restrict__ shortcut,
    float* __restrict__ outf, __bf16* __restrict__ zbf, __bf16* __restrict__ xbf,
    __bf16* __restrict__ gbf, __bf16* __restrict__ qbf, __bf16* __restrict__ kbf) {
  __shared__ __bf16 As[2][128 * 32];
  __shared__ __bf16 Bs[2][128 * 32];

  const int tid = threadIdx.x;
  const int lane = tid & 63, wid = tid >> 6;   // wid 0..7
  const int wr = wid >> 1, wc = wid & 1;       // 4 x 2 waves, wave tile 32(m) x 64(n)

  // XCD-aware bijective swizzle (grid sizes are multiples of 8)
  const int nwg = gridDim.x;
  const int cpx = nwg >> 3;
  const int swz = (blockIdx.x & 7) * cpx + (blockIdx.x >> 3);
  const int ntx = N_out >> 7;
  const int m0 = (swz / ntx) << 7;
  const int n0 = (swz % ntx) << 7;

  f32x4 acc[2][4] = {};
  const int NT = K >> 5;

  const int arow0 = wr * 32 + (lane & 15);
  const int brow0 = wc * 64 + (lane & 15);
  const int hh = lane >> 4;

  // linear staging: 1024 16B-chunks per (A or B) half; 2 per thread
  auto stage = [&](const __bf16* src, int row0, int kt, __bf16* lbuf) {
#pragma unroll
    for (int j = 0; j < 1; ++j) {   // 512 chunks per matrix per step
      int off16 = tid + j * 512;
      int row = off16 >> 2, slot = off16 & 3;
      gload16(&src[(size_t)(row0 + row) * K + kt + slot * 8], lbuf + off16 * 8);
    }
  };
  auto fragrd = [&](const __bf16* buf, int row) -> bf16x8 {
    return *(const bf16x8*)&buf[(row << 5) + (hh << 3)];
  };

  // prologue: tile 0
  stage(A, m0, 0, &As[0][0]);
  stage(Bt, n0, 0, &Bs[0][0]);
  asm volatile("s_waitcnt vmcnt(0)" ::: "memory");
  __builtin_amdgcn_s_barrier();

  for (int t = 0; t < NT; ++t) {
    const __bf16* Ap = &As[t & 1][0];
    const __bf16* Bp = &Bs[t & 1][0];
    // issue next-tile staging first; it stays in flight under this step's
    // ds_reads + MFMAs, then drained by the single vmcnt(0).
    if (t + 1 < NT) {
      stage(A, m0, (t + 1) << 5, &As[(t + 1) & 1][0]);
      stage(Bt, n0, (t + 1) << 5, &Bs[(t + 1) & 1][0]);
    }
    {
      bf16x8 af[2], bf[4];
#pragma unroll
      for (int m = 0; m < 2; ++m) af[m] = fragrd(Ap, arow0 + m * 16);
#pragma unroll
      for (int n = 0; n < 4; ++n) bf[n] = fragrd(Bp, brow0 + n * 16);
      __builtin_amdgcn_s_setprio(1);
#pragma unroll
      for (int m = 0; m < 2; ++m)
#pragma unroll
        for (int n = 0; n < 4; ++n)
          acc[m][n] = __builtin_amdgcn_mfma_f32_16x16x32_bf16(af[m], bf[n], acc[m][n], 0, 0, 0);
      __builtin_amdgcn_s_setprio(0);
    }
    asm volatile("s_waitcnt vmcnt(0)" ::: "memory");
    __builtin_amdgcn_s_barrier();
  }

  // epilogue: C/D map col=lane&15, row=(lane>>4)*4+i
#pragma unroll
  for (int m = 0; m < 2; ++m) {
#pragma unroll
    for (int n = 0; n < 4; ++n) {
#pragma unroll
      for (int i = 0; i < 4; ++i) {
        int r = m0 + wr * 32 + m * 16 + ((lane >> 4) << 2) + i;
        int c = n0 + wc * 64 + n * 16 + (lane & 15);
        float v = acc[m][n][i];
        if (EPI == 1) {
          if (c < 1024)       zbf[(size_t)r * DM + c] = (__bf16)sigmoidf(v);
          else if (c < 2048)  xbf[(size_t)r * DM + (c - 1024)] = (__bf16)v;
          else if (c < 3072)  gbf[(size_t)r * DM + (c - 2048)] = (__bf16)sigmoidf(v + gate_bias[c - 2048]);
          else if (c < 3200)  qbf[(size_t)r * 128 + (c - 3072)] = (__bf16)v;
          else                kbf[(size_t)r * 128 + (c - 3200)] = (__bf16)v;
        } else {
          outf[(size_t)r * DM + c] = v + shortcut[(size_t)r * DM + c];
        }
      }
    }
  }
}

// ---------------- per-chunk first-order scan (f32 state), thread = one d-channel
__global__ __launch_bounds__(256) void scan_kernel(const __bf16* __restrict__ g,
                                                   const __bf16* __restrict__ x,
                                                   const __bf16* __restrict__ kin,
                                                   __bf16* __restrict__ ixa,
                                                   __bf16* __restrict__ ika) {
  int bx = blockIdx.x;            // 2*64*4 = 512 blocks
  int part = bx & 3;
  int c = (bx >> 2) & 63;
  int b = bx >> 8;
  int d = part * 256 + threadIdx.x;
  size_t base = (size_t)b * SEQ + (size_t)c * 64;
  float sx = 0.f, sk = 0.f;
  for (int t = 0; t < 64; ++t) {
    size_t row = base + t;
    float gg = (float)g[row * DM + d];
    float xv = (float)x[row * DM + d];
    float kv = (float)kin[row * 128 + (d & 127)];
    sx = gg * (sx - xv) + xv;   // = g*prev + (1-g)*x
    sk = gg * (sk - kv) + kv;
    ixa[row * DM + d] = (__bf16)sx;
    ika[row * DM + d] = (__bf16)sk;
  }
}

// ---------------- attention: block = (qtile 64 queries, head, batch); 4 waves
__global__ __launch_bounds__(256) void attn_kernel(const __bf16* __restrict__ qbf,
                                                   const __bf16* __restrict__ ixa,
                                                   const __bf16* __restrict__ ika,
                                                   const __bf16* __restrict__ zbf,
                                                   __bf16* __restrict__ y) {
  const int qt = blockIdx.x;   // 0..63 query chunk
  const int h  = blockIdx.y;   // 0..15
  const int b  = blockIdx.z;   // 0..1
  const int tid = threadIdx.x;
  const int lane = tid & 63, wd = tid >> 6;

  __shared__ __bf16 qs[64 * 72];
  __shared__ __bf16 ck[64 * 72];
  __shared__ __bf16 cxT[64 * 72];
  __shared__ __bf16 pb[64 * 72];
  __shared__ float sc[64 * 65];
  __shared__ float rden[64], iwd[64];

  const size_t base = (size_t)b * SEQ;

  for (int i = tid; i < 512; i += 256) {
    int row = i >> 3, part = i & 7;
    *(bf16x8*)&qs[row * 72 + part * 8] =
        *(const bf16x8*)&qbf[(base + qt * 64 + row) * 128 + (h & 1) * 64 + part * 8];
    *(bf16x8*)&ck[row * 72 + part * 8] =
        *(const bf16x8*)&ika[(base + (size_t)row * 64) * DM + h * 64 + part * 8];
  }
  for (int i = tid; i < 4096; i += 256) {
    int c = i & 63, j = i >> 6;
    cxT[j * 72 + c] = ixa[(base + (size_t)c * 64) * DM + h * 64 + j];
  }
  __syncthreads();

  {
    f32x4 d4[4] = {};
#pragma unroll
    for (int kk = 0; kk < 64; kk += 32) {
      bf16x8 a = *(const bf16x8*)&qs[(wd * 16 + (lane & 15)) * 72 + kk + (lane >> 4) * 8];
#pragma unroll
      for (int ni = 0; ni < 4; ++ni) {
        bf16x8 bb = *(const bf16x8*)&ck[(ni * 16 + (lane & 15)) * 72 + kk + (lane >> 4) * 8];
        d4[ni] = __builtin_amdgcn_mfma_f32_16x16x32_bf16(a, bb, d4[ni], 0, 0, 0);
      }
    }
#pragma unroll
    for (int ni = 0; ni < 4; ++ni)
#pragma unroll
      for (int i = 0; i < 4; ++i) {
        int qrow = wd * 16 + (lane >> 4) * 4 + i;
        int c = ni * 16 + (lane & 15);
        sc[qrow * 65 + c] = 0.125f * d4[ni][i];
      }
  }

  float lse = 0.f;
  if (tid < 64) {
    const __bf16* qrow = &qbf[(base + qt * 64 + tid) * 128 + (h & 1) * 64];
    const __bf16* krow = &ika[(base + qt * 64 + tid) * DM + h * 64];
    float dot = 0.f;
#pragma unroll
    for (int p = 0; p < 8; ++p) {
      bf16x8 qa = *(const bf16x8*)&qrow[p * 8];
      bf16x8 ka = *(const bf16x8*)&krow[p * 8];
#pragma unroll
      for (int e = 0; e < 8; ++e) dot += (float)qa[e] * (float)ka[e];
    }
    lse = 0.125f * dot;
  }
  __syncthreads();

  if (tid < 64) {
    int q = tid;
    float m = lse;
    for (int c = 0; c < qt; ++c) m = fmaxf(m, sc[q * 65 + c]);
    float den = 0.f;
    for (int c = 0; c < 64; ++c) {
      float wv = (c < qt) ? __expf(sc[q * 65 + c] - m) : 0.f;
      pb[q * 72 + c] = (__bf16)wv;
      den += wv;
    }
    float iw = __expf(lse - m);
    den += iw;
    rden[q] = 1.f / den;
    iwd[q] = iw;
  }
  __syncthreads();

  {
    f32x4 d4[4] = {};
#pragma unroll
    for (int kk = 0; kk < 64; kk += 32) {
      bf16x8 a = *(const bf16x8*)&pb[(wd * 16 + (lane & 15)) * 72 + kk + (lane >> 4) * 8];
#pragma unroll
      for (int ni = 0; ni < 4; ++ni) {
        bf16x8 bb = *(const bf16x8*)&cxT[(ni * 16 + (lane & 15)) * 72 + kk + (lane >> 4) * 8];
        d4[ni] = __builtin_amdgcn_mfma_f32_16x16x32_bf16(a, bb, d4[ni], 0, 0, 0);
      }
    }
#pragma unroll
    for (int ni = 0; ni < 4; ++ni)
#pragma unroll
      for (int i = 0; i < 4; ++i) {
        int qrow = wd * 16 + (lane >> 4) * 4 + i;
        int j = ni * 16 + (lane & 15);
        size_t srow = base + qt * 64 + qrow;
        float ix = (float)ixa[srow * DM + h * 64 + j];
        float outv = (d4[ni][i] + iwd[qrow] * ix) * rden[qrow];
        float zv = (float)zbf[srow * DM + h * 64 + j];
        y[srow * DM + h * 64 + j] = (__bf16)(outv * zv);
      }
  }
}

// ---------------- launcher
extern "C" void kernel_launch(void* const* d_in, const int* in_sizes, int n_in,
                              void* d_out, int out_size, void* d_ws, size_t ws_size,
                              hipStream_t stream) {
  const float* hidden = (const float*)d_in[0];
  const float* rmsw   = (const float*)d_in[1];
  const float* Win    = (const float*)d_in[2];
  const float* gbias  = (const float*)d_in[3];
  const float* Wout   = (const float*)d_in[4];
  float* out = (float*)d_out;

  char* ws = (char*)d_ws;
  size_t o = 0;
  auto alloc = [&](size_t bytes) { char* p = ws + o; o += (bytes + 255) & ~(size_t)255; return p; };
  __bf16* WinT  = (__bf16*)alloc((size_t)PD * DM * 2);
  __bf16* WoutT = (__bf16*)alloc((size_t)DM * DM * 2);
  __bf16* hy    = (__bf16*)alloc((size_t)TROWS * DM * 2);  // h_bf, reused as y after GEMM1
  __bf16* zbf   = (__bf16*)alloc((size_t)TROWS * DM * 2);
  __bf16* xbf   = (__bf16*)alloc((size_t)TROWS * DM * 2);
  __bf16* gbf   = (__bf16*)alloc((size_t)TROWS * DM * 2);
  __bf16* qbf   = (__bf16*)alloc((size_t)TROWS * 128 * 2);
  __bf16* kbf   = (__bf16*)alloc((size_t)TROWS * 128 * 2);
  __bf16* ixa   = (__bf16*)alloc((size_t)TROWS * DM * 2);
  __bf16* ika   = (__bf16*)alloc((size_t)TROWS * DM * 2);

  tcvt_kernel<<<dim3(PD / 32, DM / 32), dim3(32, 8), 0, stream>>>(Win, WinT, DM, PD);
  tcvt_kernel<<<dim3(DM / 32, DM / 32), dim3(32, 8), 0, stream>>>(Wout, WoutT, DM, DM);
  rmsnorm_kernel<<<TROWS, 256, 0, stream>>>(hidden, rmsw, hy);
  // GEMM1: M=8192, N=3328 -> 64*26 = 1664 blocks (1664 % 8 == 0)
  gemm2p<1><<<dim3((TROWS / 128) * (PD / 128)), 512, 0, stream>>>(
      hy, WinT, PD, DM, gbias, nullptr, nullptr, zbf, xbf, gbf, qbf, kbf);
  scan_kernel<<<512, 256, 0, stream>>>(gbf, xbf, kbf, ixa, ika);
  attn_kernel<<<dim3(64, 16, 2), 256, 0, stream>>>(qbf, ixa, ika, zbf, hy);
  // GEMM2: M=8192, N=1024 -> 64*8 = 512 blocks (512 % 8 == 0)
  gemm2p<0><<<dim3((TROWS / 128) * (DM / 128)), 512, 0, stream>>>(
      hy, WoutT, DM, DM, nullptr, hidden, out, nullptr, nullptr, nullptr, nullptr, nullptr);
}

// Round 9
// 174.485 us; speedup vs baseline: 1.2547x; 1.1848x over previous
//
#include <hip/hip_runtime.h>
#include <hip/hip_bf16.h>

typedef __bf16 bf16x8 __attribute__((ext_vector_type(8)));
typedef __bf16 bf16x4 __attribute__((ext_vector_type(4)));
typedef float  f32x4  __attribute__((ext_vector_type(4)));

#define DM 1024
#define PD 3328
#define TROWS 8192   // bs*seq = 2*4096
#define SEQ 4096

__device__ __forceinline__ float sigmoidf(float x) { return 1.f / (1.f + __expf(-x)); }

__device__ __forceinline__ void gload16(const void* g, void* l) {
  __builtin_amdgcn_global_load_lds(
      (const __attribute__((address_space(1))) void*)g,
      (__attribute__((address_space(3))) void*)l, 16, 0, 0);
}

// ---------------- transpose + f32->bf16 convert:  in[K][N] f32 -> out[N][K] bf16
__global__ __launch_bounds__(256) void tcvt_kernel(const float* __restrict__ in,
                                                   __bf16* __restrict__ out,
                                                   int K, int N) {
  __shared__ float tile[32][33];
  int n0 = blockIdx.x * 32, k0 = blockIdx.y * 32;
  int tx = threadIdx.x, ty = threadIdx.y;     // 32 x 8
  for (int i = ty; i < 32; i += 8) tile[i][tx] = in[(size_t)(k0 + i) * N + n0 + tx];
  __syncthreads();
  for (int i = ty; i < 32; i += 8) out[(size_t)(n0 + i) * K + k0 + tx] = (__bf16)tile[tx][i];
}

// ---------------- RMSNorm -> bf16
__global__ __launch_bounds__(256) void rmsnorm_kernel(const float* __restrict__ hidden,
                                                      const float* __restrict__ w,
                                                      __bf16* __restrict__ hbf) {
  int r = blockIdx.x;
  int tid = threadIdx.x;
  float4 v = ((const float4*)(hidden + (size_t)r * DM))[tid];
  float ss = v.x * v.x + v.y * v.y + v.z * v.z + v.w * v.w;
#pragma unroll
  for (int off = 32; off > 0; off >>= 1) ss += __shfl_xor(ss, off);
  __shared__ float wsum[4];
  int lane = tid & 63, wid = tid >> 6;
  if (lane == 0) wsum[wid] = ss;
  __syncthreads();
  float tot = wsum[0] + wsum[1] + wsum[2] + wsum[3];
  float inv = rsqrtf(tot * (1.f / 1024.f) + 1e-6f);
  float4 wl = ((const float4*)w)[tid];
  bf16x4 o;
  o[0] = (__bf16)(v.x * inv * wl.x);
  o[1] = (__bf16)(v.y * inv * wl.y);
  o[2] = (__bf16)(v.z * inv * wl.z);
  o[3] = (__bf16)(v.w * inv * wl.w);
  *(bf16x4*)(hbf + (size_t)r * DM + tid * 4) = o;
}

// ---------------- 2-phase MFMA GEMM, 128x128 tile, BK=64, dbuf LDS (64 KiB),
// ONE barrier per K-step, 512 threads / 8 waves (wave tile 32x64),
// 2 blocks/CU. R6-verified config: 94 us GEMM1, 0 bank conflicts.
template <int EPI>
__global__ __launch_bounds__(512, 4) void gemm2p(
    const __bf16* __restrict__ A, const __bf16* __restrict__ Bt,
    int N_out, int K,
    const float* __restrict__ gate_bias, const float* __restrict__ shortcut,
    float* __restrict__ outf, __bf16* __restrict__ zbf, __bf16* __restrict__ xbf,
    __bf16* __restrict__ gbf, __bf16* __restrict__ qbf, __bf16* __restrict__ kbf) {
  __shared__ __bf16 As[2][128 * 64];
  __shared__ __bf16 Bs[2][128 * 64];

  const int tid = threadIdx.x;
  const int lane = tid & 63, wid = tid >> 6;   // wid 0..7
  const int wr = wid >> 1, wc = wid & 1;       // 4 x 2 waves, wave tile 32(m) x 64(n)

  // XCD-aware bijective swizzle (grid sizes are multiples of 8)
  const int nwg = gridDim.x;
  const int cpx = nwg >> 3;
  const int swz = (blockIdx.x & 7) * cpx + (blockIdx.x >> 3);
  const int ntx = N_out >> 7;
  const int m0 = (swz / ntx) << 7;
  const int n0 = (swz % ntx) << 7;

  f32x4 acc[2][4] = {};
  const int NT = K >> 6;

  const int arow0 = wr * 32 + (lane & 15);
  const int brow0 = wc * 64 + (lane & 15);

  auto stage = [&](const __bf16* src, int row0, int kt, __bf16* lbuf) {
#pragma unroll
    for (int j = 0; j < 2; ++j) {
      int off16 = tid + j * 512;        // 16B-chunk index; 8 chunks per row
      int row = off16 >> 3, slot = off16 & 7;
      int col = (slot ^ (row & 7)) << 3;  // inverse swizzle on the SOURCE
      gload16(&src[(size_t)(row0 + row) * K + kt + col], lbuf + off16 * 8);
    }
  };
  auto fragrd = [&](const __bf16* buf, int row, int ks) -> bf16x8 {
    int s = ((ks << 2) + (lane >> 4)) ^ (row & 7);   // swizzled read
    return *(const bf16x8*)&buf[(row << 6) + (s << 3)];
  };

  // prologue: tile 0
  stage(A, m0, 0, &As[0][0]);
  stage(Bt, n0, 0, &Bs[0][0]);
  asm volatile("s_waitcnt vmcnt(0)" ::: "memory");
  __builtin_amdgcn_s_barrier();

  for (int t = 0; t < NT; ++t) {
    const __bf16* Ap = &As[t & 1][0];
    const __bf16* Bp = &Bs[t & 1][0];
    if (t + 1 < NT) {
      stage(A, m0, (t + 1) << 6, &As[(t + 1) & 1][0]);
      stage(Bt, n0, (t + 1) << 6, &Bs[(t + 1) & 1][0]);
    }
#pragma unroll
    for (int ks = 0; ks < 2; ++ks) {
      bf16x8 af[2], bf[4];
#pragma unroll
      for (int m = 0; m < 2; ++m) af[m] = fragrd(Ap, arow0 + m * 16, ks);
#pragma unroll
      for (int n = 0; n < 4; ++n) bf[n] = fragrd(Bp, brow0 + n * 16, ks);
      __builtin_amdgcn_s_setprio(1);
#pragma unroll
      for (int m = 0; m < 2; ++m)
#pragma unroll
        for (int n = 0; n < 4; ++n)
          acc[m][n] = __builtin_amdgcn_mfma_f32_16x16x32_bf16(af[m], bf[n], acc[m][n], 0, 0, 0);
      __builtin_amdgcn_s_setprio(0);
    }
    asm volatile("s_waitcnt vmcnt(0)" ::: "memory");
    __builtin_amdgcn_s_barrier();
  }

  // epilogue: C/D map col=lane&15, row=(lane>>4)*4+i
#pragma unroll
  for (int m = 0; m < 2; ++m) {
#pragma unroll
    for (int n = 0; n < 4; ++n) {
#pragma unroll
      for (int i = 0; i < 4; ++i) {
        int r = m0 + wr * 32 + m * 16 + ((lane >> 4) << 2) + i;
        int c = n0 + wc * 64 + n * 16 + (lane & 15);
        float v = acc[m][n][i];
        if (EPI == 1) {
          if (c < 1024)       zbf[(size_t)r * DM + c] = (__bf16)sigmoidf(v);
          else if (c < 2048)  xbf[(size_t)r * DM + (c - 1024)] = (__bf16)v;
          else if (c < 3072)  gbf[(size_t)r * DM + (c - 2048)] = (__bf16)sigmoidf(v + gate_bias[c - 2048]);
          else if (c < 3200)  qbf[(size_t)r * 128 + (c - 3072)] = (__bf16)v;
          else                kbf[(size_t)r * 128 + (c - 3200)] = (__bf16)v;
        } else {
          outf[(size_t)r * DM + c] = v + shortcut[(size_t)r * DM + c];
        }
      }
    }
  }
}

// ---------------- per-chunk first-order scan; also emits chunk_x TRANSPOSED
// (cxtg[b][d][c] = intra_x at t=0 of chunk c) so attention can stage it
// with coalesced reads instead of 4096 scattered 2B loads per block.
__global__ __launch_bounds__(256) void scan_kernel(const __bf16* __restrict__ g,
                                                   const __bf16* __restrict__ x,
                                                   const __bf16* __restrict__ kin,
                                                   __bf16* __restrict__ ixa,
                                                   __bf16* __restrict__ ika,
                                                   __bf16* __restrict__ cxtg) {
  int bx = blockIdx.x;            // 2*64*4 = 512 blocks
  int part = bx & 3;
  int c = (bx >> 2) & 63;
  int b = bx >> 8;
  int d = part * 256 + threadIdx.x;
  size_t base = (size_t)b * SEQ + (size_t)c * 64;
  float sx = 0.f, sk = 0.f;
  for (int t = 0; t < 64; ++t) {
    size_t row = base + t;
    float gg = (float)g[row * DM + d];
    float xv = (float)x[row * DM + d];
    float kv = (float)kin[row * 128 + (d & 127)];
    sx = gg * (sx - xv) + xv;   // = g*prev + (1-g)*x
    sk = gg * (sk - kv) + kv;
    ixa[row * DM + d] = (__bf16)sx;
    ika[row * DM + d] = (__bf16)sk;
    if (t == 0) cxtg[((size_t)b * DM + d) * 64 + c] = (__bf16)sx;
  }
}

// ---------------- attention v2: block = (qtile, head, batch); 4 waves.
// All staging coalesced; lse + softmax wave-parallel (4 lanes per q-row).
__global__ __launch_bounds__(256) void attn_kernel(const __bf16* __restrict__ qbf,
                                                   const __bf16* __restrict__ ixa,
                                                   const __bf16* __restrict__ ika,
                                                   const __bf16* __restrict__ cxtg,
                                                   const __bf16* __restrict__ zbf,
                                                   __bf16* __restrict__ y) {
  const int qt = blockIdx.x;   // 0..63 query chunk
  const int h  = blockIdx.y;   // 0..15
  const int b  = blockIdx.z;   // 0..1
  const int tid = threadIdx.x;
  const int lane = tid & 63, wd = tid >> 6;

  __shared__ __bf16 qs[64 * 72];    // q rows [s][d]
  __shared__ __bf16 ck[64 * 72];    // chunk_k rows [c][d]
  __shared__ __bf16 cxT[64 * 72];   // chunk_x transposed [j][c]
  __shared__ __bf16 pb[64 * 72];    // softmax weights [s][c]
  __shared__ float sc[64 * 65];     // scores [s][c]
  __shared__ float rden[64], iwd[64], rlse[64];

  const size_t base = (size_t)b * SEQ;

  // stage Q rows, chunk_k rows, and cxT rows — all coalesced bf16x8
  for (int i = tid; i < 512; i += 256) {
    int row = i >> 3, part = i & 7;
    *(bf16x8*)&qs[row * 72 + part * 8] =
        *(const bf16x8*)&qbf[(base + qt * 64 + row) * 128 + (h & 1) * 64 + part * 8];
    *(bf16x8*)&ck[row * 72 + part * 8] =
        *(const bf16x8*)&ika[(base + (size_t)row * 64) * DM + h * 64 + part * 8];
    *(bf16x8*)&cxT[row * 72 + part * 8] =
        *(const bf16x8*)&cxtg[((size_t)b * DM + h * 64 + row) * 64 + part * 8];
  }
  __syncthreads();

  // scores = scale * Q . chunk_k^T  -> sc[s][c]
  {
    f32x4 d4[4] = {};
#pragma unroll
    for (int kk = 0; kk < 64; kk += 32) {
      bf16x8 a = *(const bf16x8*)&qs[(wd * 16 + (lane & 15)) * 72 + kk + (lane >> 4) * 8];
#pragma unroll
      for (int ni = 0; ni < 4; ++ni) {
        bf16x8 bb = *(const bf16x8*)&ck[(ni * 16 + (lane & 15)) * 72 + kk + (lane >> 4) * 8];
        d4[ni] = __builtin_amdgcn_mfma_f32_16x16x32_bf16(a, bb, d4[ni], 0, 0, 0);
      }
    }
#pragma unroll
    for (int ni = 0; ni < 4; ++ni)
#pragma unroll
      for (int i = 0; i < 4; ++i) {
        int qrow = wd * 16 + (lane >> 4) * 4 + i;
        int c = ni * 16 + (lane & 15);
        sc[qrow * 65 + c] = 0.125f * d4[ni][i];
      }
  }

  // intra_lse, 4 lanes per q-row: thread (s=tid>>2, p=tid&3) does 16 dims
  {
    int s = tid >> 2, p = tid & 3;
    const __bf16* krow = &ika[(base + qt * 64 + s) * DM + h * 64 + p * 16];
    float dot = 0.f;
#pragma unroll
    for (int half = 0; half < 2; ++half) {
      bf16x8 qa = *(const bf16x8*)&qs[s * 72 + p * 16 + half * 8];
      bf16x8 ka = *(const bf16x8*)&krow[half * 8];
#pragma unroll
      for (int e = 0; e < 8; ++e) dot += (float)qa[e] * (float)ka[e];
    }
    dot += __shfl_xor(dot, 1);
    dot += __shfl_xor(dot, 2);
    if (p == 0) rlse[s] = 0.125f * dot;
  }
  __syncthreads();

  // softmax, 4 lanes per q-row: thread (s,p) handles c in [p*16, p*16+16)
  {
    int s = tid >> 2, p = tid & 3;
    float lse = rlse[s];
    float m = -1e30f;
#pragma unroll
    for (int k = 0; k < 16; ++k) {
      int c = p * 16 + k;
      if (c < qt) m = fmaxf(m, sc[s * 65 + c]);
    }
    m = fmaxf(m, __shfl_xor(m, 1));
    m = fmaxf(m, __shfl_xor(m, 2));
    m = fmaxf(m, lse);
    float den = 0.f;
    bf16x8 w0, w1;
#pragma unroll
    for (int k = 0; k < 16; ++k) {
      int c = p * 16 + k;
      float wv = (c < qt) ? __expf(sc[s * 65 + c] - m) : 0.f;
      if (k < 8) w0[k] = (__bf16)wv; else w1[k - 8] = (__bf16)wv;
      den += wv;
    }
    *(bf16x8*)&pb[s * 72 + p * 16] = w0;
    *(bf16x8*)&pb[s * 72 + p * 16 + 8] = w1;
    den += __shfl_xor(den, 1);
    den += __shfl_xor(den, 2);
    float iw = __expf(lse - m);
    if (p == 0) {
      rden[s] = 1.f / (den + iw);
      iwd[s] = iw;
    }
  }
  __syncthreads();

  // PV: out[s][j] = sum_c pb[s][c] * cxT[j][c]
  {
    f32x4 d4[4] = {};
#pragma unroll
    for (int kk = 0; kk < 64; kk += 32) {
      bf16x8 a = *(const bf16x8*)&pb[(wd * 16 + (lane & 15)) * 72 + kk + (lane >> 4) * 8];
#pragma unroll
      for (int ni = 0; ni < 4; ++ni) {
        bf16x8 bb = *(const bf16x8*)&cxT[(ni * 16 + (lane & 15)) * 72 + kk + (lane >> 4) * 8];
        d4[ni] = __builtin_amdgcn_mfma_f32_16x16x32_bf16(a, bb, d4[ni], 0, 0, 0);
      }
    }
#pragma unroll
    for (int ni = 0; ni < 4; ++ni)
#pragma unroll
      for (int i = 0; i < 4; ++i) {
        int qrow = wd * 16 + (lane >> 4) * 4 + i;
        int j = ni * 16 + (lane & 15);
        size_t srow = base + qt * 64 + qrow;
        float ix = (float)ixa[srow * DM + h * 64 + j];
        float outv = (d4[ni][i] + iwd[qrow] * ix) * rden[qrow];
        float zv = (float)zbf[srow * DM + h * 64 + j];
        y[srow * DM + h * 64 + j] = (__bf16)(outv * zv);
      }
  }
}

// ---------------- launcher
extern "C" void kernel_launch(void* const* d_in, const int* in_sizes, int n_in,
                              void* d_out, int out_size, void* d_ws, size_t ws_size,
                              hipStream_t stream) {
  const float* hidden = (const float*)d_in[0];
  const float* rmsw   = (const float*)d_in[1];
  const float* Win    = (const float*)d_in[2];
  const float* gbias  = (const float*)d_in[3];
  const float* Wout   = (const float*)d_in[4];
  float* out = (float*)d_out;

  char* ws = (char*)d_ws;
  size_t o = 0;
  auto alloc = [&](size_t bytes) { char* p = ws + o; o += (bytes + 255) & ~(size_t)255; return p; };
  __bf16* WinT  = (__bf16*)alloc((size_t)PD * DM * 2);
  __bf16* WoutT = (__bf16*)alloc((size_t)DM * DM * 2);
  __bf16* hy    = (__bf16*)alloc((size_t)TROWS * DM * 2);  // h_bf, reused as y after GEMM1
  __bf16* zbf   = (__bf16*)alloc((size_t)TROWS * DM * 2);
  __bf16* xbf   = (__bf16*)alloc((size_t)TROWS * DM * 2);
  __bf16* gbf   = (__bf16*)alloc((size_t)TROWS * DM * 2);
  __bf16* qbf   = (__bf16*)alloc((size_t)TROWS * 128 * 2);
  __bf16* kbf   = (__bf16*)alloc((size_t)TROWS * 128 * 2);
  __bf16* ixa   = (__bf16*)alloc((size_t)TROWS * DM * 2);
  __bf16* ika   = (__bf16*)alloc((size_t)TROWS * DM * 2);
  __bf16* cxtg  = (__bf16*)alloc((size_t)2 * DM * 64 * 2);

  tcvt_kernel<<<dim3(PD / 32, DM / 32), dim3(32, 8), 0, stream>>>(Win, WinT, DM, PD);
  tcvt_kernel<<<dim3(DM / 32, DM / 32), dim3(32, 8), 0, stream>>>(Wout, WoutT, DM, DM);
  rmsnorm_kernel<<<TROWS, 256, 0, stream>>>(hidden, rmsw, hy);
  // GEMM1: M=8192, N=3328 -> 64*26 = 1664 blocks (1664 % 8 == 0)
  gemm2p<1><<<dim3((TROWS / 128) * (PD / 128)), 512, 0, stream>>>(
      hy, WinT, PD, DM, gbias, nullptr, nullptr, zbf, xbf, gbf, qbf, kbf);
  scan_kernel<<<512, 256, 0, stream>>>(gbf, xbf, kbf, ixa, ika, cxtg);
  attn_kernel<<<dim3(64, 16, 2), 256, 0, stream>>>(qbf, ixa, ika, cxtg, zbf, hy);
  // GEMM2: M=8192, N=1024 -> 64*8 = 512 blocks (512 % 8 == 0)
  gemm2p<0><<<dim3((TROWS / 128) * (DM / 128)), 512, 0, stream>>>(
      hy, WoutT, DM, DM, nullptr, hidden, out, nullptr, nullptr, nullptr, nullptr, nullptr);
}

// Round 10
// 169.948 us; speedup vs baseline: 1.2882x; 1.0267x over previous
//
#include <hip/hip_runtime.h>
#include <hip/hip_bf16.h>

typedef __bf16 bf16x8 __attribute__((ext_vector_type(8)));
typedef __bf16 bf16x4 __attribute__((ext_vector_type(4)));
typedef float  f32x4  __attribute__((ext_vector_type(4)));

#define DM 1024
#define PD 3328
#define TROWS 8192   // bs*seq = 2*4096
#define SEQ 4096

__device__ __forceinline__ float sigmoidf(float x) { return 1.f / (1.f + __expf(-x)); }

__device__ __forceinline__ void gload16(const void* g, void* l) {
  __builtin_amdgcn_global_load_lds(
      (const __attribute__((address_space(1))) void*)g,
      (__attribute__((address_space(3))) void*)l, 16, 0, 0);
}

// ---------------- fused prep: tcvt(Win) + tcvt(Wout) + rmsnorm in ONE launch
// blocks [0, 3328): transpose+cvt Win (1024 x 3328 f32 -> 3328 x 1024 bf16)
// blocks [3328, 4352): transpose+cvt Wout (1024x1024)
// blocks [4352, 12544): rmsnorm rows
__global__ __launch_bounds__(256) void prep_kernel(const float* __restrict__ Win,
                                                   __bf16* __restrict__ WinT,
                                                   const float* __restrict__ Wout,
                                                   __bf16* __restrict__ WoutT,
                                                   const float* __restrict__ hidden,
                                                   const float* __restrict__ rmsw,
                                                   __bf16* __restrict__ hbf) {
  const int id = blockIdx.x;
  const int tid = threadIdx.x;
  if (id < 4352) {
    __shared__ float tile[32][33];
    const float* in;  __bf16* out;  int K, N, bx, by;
    if (id < 3328) { in = Win;  out = WinT;  K = DM; N = PD; bx = id % 104; by = id / 104; }
    else           { in = Wout; out = WoutT; K = DM; N = DM; bx = (id - 3328) & 31; by = (id - 3328) >> 5; }
    int n0 = bx * 32, k0 = by * 32;
    int tx = tid & 31, ty = tid >> 5;   // 32 x 8
    for (int i = ty; i < 32; i += 8) tile[i][tx] = in[(size_t)(k0 + i) * N + n0 + tx];
    __syncthreads();
    for (int i = ty; i < 32; i += 8) out[(size_t)(n0 + i) * K + k0 + tx] = (__bf16)tile[tx][i];
  } else {
    int r = id - 4352;
    float4 v = ((const float4*)(hidden + (size_t)r * DM))[tid];
    float ss = v.x * v.x + v.y * v.y + v.z * v.z + v.w * v.w;
#pragma unroll
    for (int off = 32; off > 0; off >>= 1) ss += __shfl_xor(ss, off);
    __shared__ float wsum[4];
    int lane = tid & 63, wid = tid >> 6;
    if (lane == 0) wsum[wid] = ss;
    __syncthreads();
    float tot = wsum[0] + wsum[1] + wsum[2] + wsum[3];
    float inv = rsqrtf(tot * (1.f / 1024.f) + 1e-6f);
    float4 wl = ((const float4*)rmsw)[tid];
    bf16x4 o;
    o[0] = (__bf16)(v.x * inv * wl.x);
    o[1] = (__bf16)(v.y * inv * wl.y);
    o[2] = (__bf16)(v.z * inv * wl.z);
    o[3] = (__bf16)(v.w * inv * wl.w);
    *(bf16x4*)(hbf + (size_t)r * DM + tid * 4) = o;
  }
}

// ---------------- 2-phase MFMA GEMM, 128x128 tile, BK=64, dbuf LDS (64 KiB),
// ONE barrier per K-step, 512 threads / 8 waves, 2 blocks/CU (R6-verified).
// NEW: grouped 8m x GN n tile mapping under the XCD swizzle so the concurrent
// window's working set (8 A-panels + GN B-tiles ~ 4-5 MB) fits one XCD's L2.
template <int GN, int EPI>
__global__ __launch_bounds__(512, 4) void gemm2p(
    const __bf16* __restrict__ A, const __bf16* __restrict__ Bt,
    int N_out, int K,
    const float* __restrict__ gate_bias, const float* __restrict__ shortcut,
    float* __restrict__ outf, __bf16* __restrict__ zbf, __bf16* __restrict__ xbf,
    __bf16* __restrict__ gbf, __bf16* __restrict__ qbf, __bf16* __restrict__ kbf) {
  __shared__ __bf16 As[2][128 * 64];
  __shared__ __bf16 Bs[2][128 * 64];

  const int tid = threadIdx.x;
  const int lane = tid & 63, wid = tid >> 6;   // wid 0..7
  const int wr = wid >> 1, wc = wid & 1;       // 4 x 2 waves, wave tile 32(m) x 64(n)

  // XCD-aware bijective swizzle (grid sizes are multiples of 8)
  const int nwg = gridDim.x;
  const int cpx = nwg >> 3;
  const int swz = (blockIdx.x & 7) * cpx + (blockIdx.x >> 3);
  // grouped 2D mapping: group = 8(m) x GN(n) tiles, m-major groups
  const int ntx = N_out >> 7;
  const int ngn = ntx / GN;
  const int g = swz / (8 * GN), l = swz % (8 * GN);
  const int gm = g / ngn, gn = g % ngn;
  const int m0 = (gm * 8 + (l & 7)) << 7;
  const int n0 = (gn * GN + (l >> 3)) << 7;

  f32x4 acc[2][4] = {};
  const int NT = K >> 6;

  const int arow0 = wr * 32 + (lane & 15);
  const int brow0 = wc * 64 + (lane & 15);

  auto stage = [&](const __bf16* src, int row0, int kt, __bf16* lbuf) {
#pragma unroll
    for (int j = 0; j < 2; ++j) {
      int off16 = tid + j * 512;        // 16B-chunk index; 8 chunks per row
      int row = off16 >> 3, slot = off16 & 7;
      int col = (slot ^ (row & 7)) << 3;  // inverse swizzle on the SOURCE
      gload16(&src[(size_t)(row0 + row) * K + kt + col], lbuf + off16 * 8);
    }
  };
  auto fragrd = [&](const __bf16* buf, int row, int ks) -> bf16x8 {
    int s = ((ks << 2) + (lane >> 4)) ^ (row & 7);   // swizzled read
    return *(const bf16x8*)&buf[(row << 6) + (s << 3)];
  };

  // prologue: tile 0
  stage(A, m0, 0, &As[0][0]);
  stage(Bt, n0, 0, &Bs[0][0]);
  asm volatile("s_waitcnt vmcnt(0)" ::: "memory");
  __builtin_amdgcn_s_barrier();

  for (int t = 0; t < NT; ++t) {
    const __bf16* Ap = &As[t & 1][0];
    const __bf16* Bp = &Bs[t & 1][0];
    if (t + 1 < NT) {
      stage(A, m0, (t + 1) << 6, &As[(t + 1) & 1][0]);
      stage(Bt, n0, (t + 1) << 6, &Bs[(t + 1) & 1][0]);
    }
#pragma unroll
    for (int ks = 0; ks < 2; ++ks) {
      bf16x8 af[2], bf[4];
#pragma unroll
      for (int m = 0; m < 2; ++m) af[m] = fragrd(Ap, arow0 + m * 16, ks);
#pragma unroll
      for (int n = 0; n < 4; ++n) bf[n] = fragrd(Bp, brow0 + n * 16, ks);
      __builtin_amdgcn_s_setprio(1);
#pragma unroll
      for (int m = 0; m < 2; ++m)
#pragma unroll
        for (int n = 0; n < 4; ++n)
          acc[m][n] = __builtin_amdgcn_mfma_f32_16x16x32_bf16(af[m], bf[n], acc[m][n], 0, 0, 0);
      __builtin_amdgcn_s_setprio(0);
    }
    asm volatile("s_waitcnt vmcnt(0)" ::: "memory");
    __builtin_amdgcn_s_barrier();
  }

  // epilogue: C/D map col=lane&15, row=(lane>>4)*4+i
#pragma unroll
  for (int m = 0; m < 2; ++m) {
#pragma unroll
    for (int n = 0; n < 4; ++n) {
#pragma unroll
      for (int i = 0; i < 4; ++i) {
        int r = m0 + wr * 32 + m * 16 + ((lane >> 4) << 2) + i;
        int c = n0 + wc * 64 + n * 16 + (lane & 15);
        float v = acc[m][n][i];
        if (EPI == 1) {
          if (c < 1024)       zbf[(size_t)r * DM + c] = (__bf16)sigmoidf(v);
          else if (c < 2048)  xbf[(size_t)r * DM + (c - 1024)] = (__bf16)v;
          else if (c < 3072)  gbf[(size_t)r * DM + (c - 2048)] = (__bf16)sigmoidf(v + gate_bias[c - 2048]);
          else if (c < 3200)  qbf[(size_t)r * 128 + (c - 3072)] = (__bf16)v;
          else                kbf[(size_t)r * 128 + (c - 3200)] = (__bf16)v;
        } else {
          outf[(size_t)r * DM + c] = v + shortcut[(size_t)r * DM + c];
        }
      }
    }
  }
}

// ---------------- per-chunk first-order scan; also emits chunk_x TRANSPOSED
__global__ __launch_bounds__(256) void scan_kernel(const __bf16* __restrict__ g,
                                                   const __bf16* __restrict__ x,
                                                   const __bf16* __restrict__ kin,
                                                   __bf16* __restrict__ ixa,
                                                   __bf16* __restrict__ ika,
                                                   __bf16* __restrict__ cxtg) {
  int bx = blockIdx.x;            // 2*64*4 = 512 blocks
  int part = bx & 3;
  int c = (bx >> 2) & 63;
  int b = bx >> 8;
  int d = part * 256 + threadIdx.x;
  size_t base = (size_t)b * SEQ + (size_t)c * 64;
  float sx = 0.f, sk = 0.f;
  for (int t = 0; t < 64; ++t) {
    size_t row = base + t;
    float gg = (float)g[row * DM + d];
    float xv = (float)x[row * DM + d];
    float kv = (float)kin[row * 128 + (d & 127)];
    sx = gg * (sx - xv) + xv;   // = g*prev + (1-g)*x
    sk = gg * (sk - kv) + kv;
    ixa[row * DM + d] = (__bf16)sx;
    ika[row * DM + d] = (__bf16)sk;
    if (t == 0) cxtg[((size_t)b * DM + d) * 64 + c] = (__bf16)sx;
  }
}

// ---------------- attention v2: block = (qtile, head, batch); 4 waves.
__global__ __launch_bounds__(256) void attn_kernel(const __bf16* __restrict__ qbf,
                                                   const __bf16* __restrict__ ixa,
                                                   const __bf16* __restrict__ ika,
                                                   const __bf16* __restrict__ cxtg,
                                                   const __bf16* __restrict__ zbf,
                                                   __bf16* __restrict__ y) {
  const int qt = blockIdx.x;   // 0..63 query chunk
  const int h  = blockIdx.y;   // 0..15
  const int b  = blockIdx.z;   // 0..1
  const int tid = threadIdx.x;
  const int lane = tid & 63, wd = tid >> 6;

  __shared__ __bf16 qs[64 * 72];    // q rows [s][d]
  __shared__ __bf16 ck[64 * 72];    // chunk_k rows [c][d]
  __shared__ __bf16 cxT[64 * 72];   // chunk_x transposed [j][c]
  __shared__ __bf16 pb[64 * 72];    // softmax weights [s][c]
  __shared__ float sc[64 * 65];     // scores [s][c]
  __shared__ float rden[64], iwd[64], rlse[64];

  const size_t base = (size_t)b * SEQ;

  for (int i = tid; i < 512; i += 256) {
    int row = i >> 3, part = i & 7;
    *(bf16x8*)&qs[row * 72 + part * 8] =
        *(const bf16x8*)&qbf[(base + qt * 64 + row) * 128 + (h & 1) * 64 + part * 8];
    *(bf16x8*)&ck[row * 72 + part * 8] =
        *(const bf16x8*)&ika[(base + (size_t)row * 64) * DM + h * 64 + part * 8];
    *(bf16x8*)&cxT[row * 72 + part * 8] =
        *(const bf16x8*)&cxtg[((size_t)b * DM + h * 64 + row) * 64 + part * 8];
  }
  __syncthreads();

  // scores = scale * Q . chunk_k^T  -> sc[s][c]
  {
    f32x4 d4[4] = {};
#pragma unroll
    for (int kk = 0; kk < 64; kk += 32) {
      bf16x8 a = *(const bf16x8*)&qs[(wd * 16 + (lane & 15)) * 72 + kk + (lane >> 4) * 8];
#pragma unroll
      for (int ni = 0; ni < 4; ++ni) {
        bf16x8 bb = *(const bf16x8*)&ck[(ni * 16 + (lane & 15)) * 72 + kk + (lane >> 4) * 8];
        d4[ni] = __builtin_amdgcn_mfma_f32_16x16x32_bf16(a, bb, d4[ni], 0, 0, 0);
      }
    }
#pragma unroll
    for (int ni = 0; ni < 4; ++ni)
#pragma unroll
      for (int i = 0; i < 4; ++i) {
        int qrow = wd * 16 + (lane >> 4) * 4 + i;
        int c = ni * 16 + (lane & 15);
        sc[qrow * 65 + c] = 0.125f * d4[ni][i];
      }
  }

  // intra_lse, 4 lanes per q-row
  {
    int s = tid >> 2, p = tid & 3;
    const __bf16* krow = &ika[(base + qt * 64 + s) * DM + h * 64 + p * 16];
    float dot = 0.f;
#pragma unroll
    for (int half = 0; half < 2; ++half) {
      bf16x8 qa = *(const bf16x8*)&qs[s * 72 + p * 16 + half * 8];
      bf16x8 ka = *(const bf16x8*)&krow[half * 8];
#pragma unroll
      for (int e = 0; e < 8; ++e) dot += (float)qa[e] * (float)ka[e];
    }
    dot += __shfl_xor(dot, 1);
    dot += __shfl_xor(dot, 2);
    if (p == 0) rlse[s] = 0.125f * dot;
  }
  __syncthreads();

  // softmax, 4 lanes per q-row
  {
    int s = tid >> 2, p = tid & 3;
    float lse = rlse[s];
    float m = -1e30f;
#pragma unroll
    for (int k = 0; k < 16; ++k) {
      int c = p * 16 + k;
      if (c < qt) m = fmaxf(m, sc[s * 65 + c]);
    }
    m = fmaxf(m, __shfl_xor(m, 1));
    m = fmaxf(m, __shfl_xor(m, 2));
    m = fmaxf(m, lse);
    float den = 0.f;
    bf16x8 w0, w1;
#pragma unroll
    for (int k = 0; k < 16; ++k) {
      int c = p * 16 + k;
      float wv = (c < qt) ? __expf(sc[s * 65 + c] - m) : 0.f;
      if (k < 8) w0[k] = (__bf16)wv; else w1[k - 8] = (__bf16)wv;
      den += wv;
    }
    *(bf16x8*)&pb[s * 72 + p * 16] = w0;
    *(bf16x8*)&pb[s * 72 + p * 16 + 8] = w1;
    den += __shfl_xor(den, 1);
    den += __shfl_xor(den, 2);
    float iw = __expf(lse - m);
    if (p == 0) {
      rden[s] = 1.f / (den + iw);
      iwd[s] = iw;
    }
  }
  __syncthreads();

  // PV: out[s][j] = sum_c pb[s][c] * cxT[j][c]
  {
    f32x4 d4[4] = {};
#pragma unroll
    for (int kk = 0; kk < 64; kk += 32) {
      bf16x8 a = *(const bf16x8*)&pb[(wd * 16 + (lane & 15)) * 72 + kk + (lane >> 4) * 8];
#pragma unroll
      for (int ni = 0; ni < 4; ++ni) {
        bf16x8 bb = *(const bf16x8*)&cxT[(ni * 16 + (lane & 15)) * 72 + kk + (lane >> 4) * 8];
        d4[ni] = __builtin_amdgcn_mfma_f32_16x16x32_bf16(a, bb, d4[ni], 0, 0, 0);
      }
    }
#pragma unroll
    for (int ni = 0; ni < 4; ++ni)
#pragma unroll
      for (int i = 0; i < 4; ++i) {
        int qrow = wd * 16 + (lane >> 4) * 4 + i;
        int j = ni * 16 + (lane & 15);
        size_t srow = base + qt * 64 + qrow;
        float ix = (float)ixa[srow * DM + h * 64 + j];
        float outv = (d4[ni][i] + iwd[qrow] * ix) * rden[qrow];
        float zv = (float)zbf[srow * DM + h * 64 + j];
        y[srow * DM + h * 64 + j] = (__bf16)(outv * zv);
      }
  }
}

// ---------------- launcher
extern "C" void kernel_launch(void* const* d_in, const int* in_sizes, int n_in,
                              void* d_out, int out_size, void* d_ws, size_t ws_size,
                              hipStream_t stream) {
  const float* hidden = (const float*)d_in[0];
  const float* rmsw   = (const float*)d_in[1];
  const float* Win    = (const float*)d_in[2];
  const float* gbias  = (const float*)d_in[3];
  const float* Wout   = (const float*)d_in[4];
  float* out = (float*)d_out;

  char* ws = (char*)d_ws;
  size_t o = 0;
  auto alloc = [&](size_t bytes) { char* p = ws + o; o += (bytes + 255) & ~(size_t)255; return p; };
  __bf16* WinT  = (__bf16*)alloc((size_t)PD * DM * 2);
  __bf16* WoutT = (__bf16*)alloc((size_t)DM * DM * 2);
  __bf16* hy    = (__bf16*)alloc((size_t)TROWS * DM * 2);  // h_bf, reused as y after GEMM1
  __bf16* zbf   = (__bf16*)alloc((size_t)TROWS * DM * 2);
  __bf16* xbf   = (__bf16*)alloc((size_t)TROWS * DM * 2);
  __bf16* gbf   = (__bf16*)alloc((size_t)TROWS * DM * 2);
  __bf16* qbf   = (__bf16*)alloc((size_t)TROWS * 128 * 2);
  __bf16* kbf   = (__bf16*)alloc((size_t)TROWS * 128 * 2);
  __bf16* ixa   = (__bf16*)alloc((size_t)TROWS * DM * 2);
  __bf16* ika   = (__bf16*)alloc((size_t)TROWS * DM * 2);
  __bf16* cxtg  = (__bf16*)alloc((size_t)2 * DM * 64 * 2);

  // fused weight-transpose + rmsnorm (3328 + 1024 + 8192 blocks)
  prep_kernel<<<dim3(12544), 256, 0, stream>>>(Win, WinT, Wout, WoutT, hidden, rmsw, hy);
  // GEMM1: M=8192, N=3328 -> 64*26 = 1664 blocks; groups 8m x 13n
  gemm2p<13, 1><<<dim3((TROWS / 128) * (PD / 128)), 512, 0, stream>>>(
      hy, WinT, PD, DM, gbias, nullptr, nullptr, zbf, xbf, gbf, qbf, kbf);
  scan_kernel<<<512, 256, 0, stream>>>(gbf, xbf, kbf, ixa, ika, cxtg);
  attn_kernel<<<dim3(64, 16, 2), 256, 0, stream>>>(qbf, ixa, ika, cxtg, zbf, hy);
  // GEMM2: M=8192, N=1024 -> 64*8 = 512 blocks; groups 8m x 8n
  gemm2p<8, 0><<<dim3((TROWS / 128) * (DM / 128)), 512, 0, stream>>>(
      hy, WoutT, DM, DM, nullptr, hidden, out, nullptr, nullptr, nullptr, nullptr, nullptr);
}